// Round 12
// baseline (57.739 us; speedup 1.0000x reference)
//
#include <hip/hip_runtime.h>

// SSIM loss, fused. in: f32 (16,3,512,512) x2; out: f32[16].
//
// r12: COLUMN-slab tiling to kill warm-up amplification.
//  * Wave = 256-col slab (4 cols/lane, one aligned float4 per img per row)
//    x 64-row strip. 3 slabs/img (bases 0/244/256; outputs 0-245/246-489/
//    490-501, per-output lo/hi mask). Col amp 1.05x, row amp 75/64=1.17x
//    vs r8-r11's 3-4x row-warm-up amplification.
//  * 1152 single-wave 64-thr blocks (4KB LDS), XCD-pinned img%8.
//  * NEW rows 3-deep register-pipelined (named bufs n1a..c, manual 3x
//    unrolled main loop -> all static indexing, no scratch). Per-CU
//    in-flight ~30KB x 256 = 7.7MB > BW*latency (5.7MB) -> latency covered.
//  * OLD row loaded same-iter (13-row reuse distance -> L1/L2 hit).
//  * Horizontal 11-window: publish 4 col-quads {s1,s2,sp,sq} to sigma-
//    permuted wave-private LDS (i*64+lane: conflict-free), read 10 halo
//    quads, slide using own sums in registers (r8 scheme, validated).
//  * Scale-folded SSIM (121^4 cancels), banked double atomics.

namespace {
constexpr int BATCH = 16;
constexpr int CHAN  = 3;
constexpr int HDIM  = 512;
constexpr int WDIM  = 512;
constexpr int WIN   = 11;
constexpr int HO    = HDIM - WIN + 1;   // 502
constexpr int WO    = WDIM - WIN + 1;   // 502
constexpr int RPS   = 64;
constexpr int NSTRIP = 8;               // strip 7 covers rows 448..501
constexpr int NSLAB = 3;
constexpr int NIMG  = BATCH * CHAN;     // 48
constexpr int NTHR  = 64;               // 1 wave per block
constexpr int NBLK  = NIMG * NSLAB * NSTRIP;   // 1152
constexpr int NBANK = 16;
// scale-folded constants: C*121^2 (121^4 cancels in n/d)
constexpr float K1 = 6.5025f  * 14641.0f;
constexpr float K2 = 58.5225f * 14641.0f;
constexpr float W2F = 121.0f;
}

__global__ __launch_bounds__(NTHR) void ssim_main(
    const float* __restrict__ g1, const float* __restrict__ g2,
    double* __restrict__ ws) {
  __shared__ float4 Q[256];              // publish: quad per slab col (4 KB)

  const int t = threadIdx.x;             // lane 0..63
  // XCD-pinned decode: img%8 == blockIdx%8
  const int xcd  = blockIdx.x & 7;
  const int qq   = blockIdx.x >> 3;      // 0..143
  const int g    = qq / (NSLAB * NSTRIP);
  const int rem  = qq % (NSLAB * NSTRIP);
  const int slab = rem >> 3;
  const int strip = rem & 7;
  const int img  = g * 8 + xcd;          // 0..47
  const int b    = img / CHAN;

  const int base = (slab == 0) ? 0 : (slab == 1 ? 244 : 256);
  const int lo   = (slab == 0) ? 0 : (slab == 1 ? 246 : 490);
  const int hi   = (slab == 0) ? 245 : (slab == 1 ? 489 : 501);

  const int r0 = strip * RPS;
  const int r1 = min(r0 + RPS, HO);
  const int c0 = base + 4 * t;           // lane's first col (16B aligned)

  const float* __restrict__ p1 = g1 + (size_t)img * HDIM * WDIM + c0;
  const float* __restrict__ p2 = g2 + (size_t)img * HDIM * WDIM + c0;

  // vertical sliding column sums, lane's 4 cols
  float s1[4], s2[4], sp[4], sq[4];
#pragma unroll
  for (int k = 0; k < 4; ++k) s1[k] = s2[k] = sp[k] = sq[k] = 0.f;

  float4 n1a, n1b, n1c, n2a, n2b, n2c;   // NEW 3-deep
  float4 o1, o2;                         // OLD

  auto ACC = [&](const float4& u, const float4& v) {
    float uu[4] = {u.x, u.y, u.z, u.w};
    float vv[4] = {v.x, v.y, v.z, v.w};
#pragma unroll
    for (int k = 0; k < 4; ++k) {
      float x = uu[k], y = vv[k];
      s1[k] += x;
      s2[k] += y;
      sp[k] = fmaf(x, y, sp[k]);
      sq[k] = fmaf(x, x, sq[k]);
      sq[k] = fmaf(y, y, sq[k]);
    }
  };
  auto DES = [&](const float4& u, const float4& v) {
    float uu[4] = {u.x, u.y, u.z, u.w};
    float vv[4] = {v.x, v.y, v.z, v.w};
#pragma unroll
    for (int k = 0; k < 4; ++k) {
      float x = uu[k], y = vv[k];
      s1[k] -= x;
      s2[k] -= y;
      sp[k] = fmaf(x, -y, sp[k]);
      sq[k] = fmaf(x, -x, sq[k]);
      sq[k] = fmaf(y, -y, sq[k]);
    }
  };

#define LDN(U, V, row)                                   \
  {                                                      \
    int rr_ = (row);                                     \
    U = *(const float4*)(p1 + (size_t)rr_ * WDIM);       \
    V = *(const float4*)(p2 + (size_t)rr_ * WDIM);       \
  }

  // ---- warm-up: accumulate rows r0..r0+9, 3-deep pipeline ----
  LDN(n1a, n2a, r0);
  LDN(n1b, n2b, r0 + 1);
  LDN(n1c, n2c, r0 + 2);
  ACC(n1a, n2a); LDN(n1a, n2a, r0 + 3);
  ACC(n1b, n2b); LDN(n1b, n2b, r0 + 4);
  ACC(n1c, n2c); LDN(n1c, n2c, r0 + 5);
  ACC(n1a, n2a); LDN(n1a, n2a, r0 + 6);
  ACC(n1b, n2b); LDN(n1b, n2b, r0 + 7);
  ACC(n1c, n2c); LDN(n1c, n2c, r0 + 8);
  ACC(n1a, n2a); LDN(n1a, n2a, r0 + 9);
  ACC(n1b, n2b); LDN(n1b, n2b, r0 + 10);
  ACC(n1c, n2c); LDN(n1c, n2c, r0 + 11);
  ACC(n1a, n2a); LDN(n1a, n2a, r0 + 12);
  // accumulated rows r0..r0+9; bufs: b=r+10, c=r+11, a=r+12 for r=r0

  float acc = 0.f;

  auto STEP = [&](int r, float4& N1, float4& N2) {
    ACC(N1, N2);                          // window = rows [r, r+10]
    LDN(N1, N2, min(r + 13, HDIM - 1));   // refill 3-deep NEW
    LDN(o1, o2, r);                       // OLD (13-row reuse: L1/L2 hit)

    // publish own 4 col-quads: sigma(4t+i) = i*64+t (conflict-free)
#pragma unroll
    for (int i = 0; i < 4; ++i)
      Q[i * 64 + t] = make_float4(s1[i], s2[i], sp[i], sq[i]);
    asm volatile("s_waitcnt lgkmcnt(0)" ::: "memory");

    // halo: col c0+4+m = quad (m&3)*64 + lane (t+1+(m>>2)), m=0..9
    float4 h[10];
#pragma unroll
    for (int m = 0; m < 10; ++m)
      h[m] = Q[(m & 3) * 64 + ((t + 1 + (m >> 2)) & 63)];

    // first window: cols c0..c0+10 = own 0..3 + halo 0..6
    float w1 = ((s1[0] + s1[1]) + (s1[2] + s1[3])) +
               ((h[0].x + h[1].x) + (h[2].x + h[3].x)) +
               ((h[4].x + h[5].x) + h[6].x);
    float w2 = ((s2[0] + s2[1]) + (s2[2] + s2[3])) +
               ((h[0].y + h[1].y) + (h[2].y + h[3].y)) +
               ((h[4].y + h[5].y) + h[6].y);
    float wp = ((sp[0] + sp[1]) + (sp[2] + sp[3])) +
               ((h[0].z + h[1].z) + (h[2].z + h[3].z)) +
               ((h[4].z + h[5].z) + h[6].z);
    float wq = ((sq[0] + sq[1]) + (sq[2] + sq[3])) +
               ((h[0].w + h[1].w) + (h[2].w + h[3].w)) +
               ((h[4].w + h[5].w) + h[6].w);

#pragma unroll
    for (int j = 0; j < 4; ++j) {
      if (j > 0) {  // slide: drop own col j-1, add halo col c0+j+10
        w1 = (w1 - s1[j - 1]) + h[6 + j].x;
        w2 = (w2 - s2[j - 1]) + h[6 + j].y;
        wp = (wp - sp[j - 1]) + h[6 + j].z;
        wq = (wq - sq[j - 1]) + h[6 + j].w;
      }
      // scale-folded SSIM (121^4 cancels in n/d)
      float s12 = w1 * w2;
      float msq = fmaf(w1, w1, w2 * w2);
      float N1_ = fmaf(2.f, s12, K1);
      float N2_ = fmaf(2.f, fmaf(W2F, wp, -s12), K2);
      float D1_ = msq + K1;
      float D2_ = fmaf(W2F, wq, -msq) + K2;
      float val = (N1_ * N2_) * __builtin_amdgcn_rcpf(D1_ * D2_);
      int c = c0 + j;
      acc += (c >= lo && c <= hi) ? val : 0.f;
    }

    DES(o1, o2);                          // slide out row r
  };

  // ---- main loop, 3x unrolled to keep buffer indices static ----
  for (int r = r0; r < r1; r += 3) {
    STEP(r, n1b, n2b);
    if (r + 1 < r1) STEP(r + 1, n1c, n2c);
    if (r + 2 < r1) STEP(r + 2, n1a, n2a);
  }
#undef LDN

  // wave reduction, banked double atomic
#pragma unroll
  for (int off = 32; off > 0; off >>= 1) acc += __shfl_down(acc, off, 64);
  if (t == 0) atomicAdd(&ws[b * NBANK + (blockIdx.x & (NBANK - 1))], (double)acc);
}

__global__ void ssim_finalize(const double* __restrict__ ws,
                              float* __restrict__ out) {
  int i = threadIdx.x;
  if (i < BATCH) {
    double s = 0.0;
#pragma unroll
    for (int k = 0; k < NBANK; ++k) s += ws[i * NBANK + k];
    out[i] = (float)(1.0 - s / ((double)CHAN * HO * WO));
  }
}

extern "C" void kernel_launch(void* const* d_in, const int* in_sizes, int n_in,
                              void* d_out, int out_size, void* d_ws,
                              size_t ws_size, hipStream_t stream) {
  const float* img1 = (const float*)d_in[0];
  const float* img2 = (const float*)d_in[1];
  float* out = (float*)d_out;
  double* ws = (double*)d_ws;

  hipMemsetAsync(d_ws, 0, BATCH * NBANK * sizeof(double), stream);
  ssim_main<<<dim3(NBLK), NTHR, 0, stream>>>(img1, img2, ws);
  ssim_finalize<<<1, 64, 0, stream>>>(ws, out);
}

// Round 13
// 55.931 us; speedup vs baseline: 1.0323x; 1.0323x over previous
//
#include <hip/hip_runtime.h>

// SSIM loss, fused. in: f32 (16,3,512,512) x2; out: f32[16].
//
// r13 = r12 column-slab structure (FETCH ~= compulsory 92MB, VGPR 56,
// no spill) with 4x the concurrency: RPS 64 -> 16.
//  * Wave = 256-col slab (4 cols/lane, aligned float4) x 16-row strip.
//    3 slabs/img (bases 0/244/256; outputs masked lo..hi per slab).
//  * 48 img x 3 slabs x 32 strips = 4608 single-wave blocks; 56 VGPR
//    (<=64 -> 8 waves/SIMD) + 4KB LDS -> ENTIRE grid co-resident:
//    ~18 waves/CU vs r12's 4.5. XCD-pinned img%8 (r10's proven FETCH fix).
//  * NEW rows 3-deep register-pipelined (named bufs, 3x unrolled loop,
//    static indexing). OLD row same-iter (13-row reuse -> L1/L2).
//  * Horizontal 11-window via sigma-permuted wave-private LDS publish
//    (4x ds_write_b128 + 10x b128 halo reads, conflict-free), slide with
//    own sums in registers. Scale-folded SSIM. Banked double atomics.

namespace {
constexpr int BATCH = 16;
constexpr int CHAN  = 3;
constexpr int HDIM  = 512;
constexpr int WDIM  = 512;
constexpr int WIN   = 11;
constexpr int HO    = HDIM - WIN + 1;   // 502
constexpr int WO    = WDIM - WIN + 1;   // 502
constexpr int RPS   = 16;
constexpr int NSTRIP = 32;              // 32*16=512 >= 502; strip31: 6 rows
constexpr int NSLAB = 3;
constexpr int NIMG  = BATCH * CHAN;     // 48
constexpr int NTHR  = 64;               // 1 wave per block
constexpr int NBLK  = NIMG * NSLAB * NSTRIP;   // 4608
constexpr int NBANK = 16;
// scale-folded constants: C*121^2 (121^4 cancels in n/d)
constexpr float K1 = 6.5025f  * 14641.0f;
constexpr float K2 = 58.5225f * 14641.0f;
constexpr float W2F = 121.0f;
}

__global__ __launch_bounds__(NTHR) void ssim_main(
    const float* __restrict__ g1, const float* __restrict__ g2,
    double* __restrict__ ws) {
  __shared__ float4 Q[256];              // publish: quad per slab col (4 KB)

  const int t = threadIdx.x;             // lane 0..63
  // XCD-pinned decode: img%8 == blockIdx%8
  const int xcd  = blockIdx.x & 7;
  const int qq   = blockIdx.x >> 3;      // 0 .. 6*NSLAB*NSTRIP-1
  const int g    = qq / (NSLAB * NSTRIP);
  const int rem  = qq % (NSLAB * NSTRIP);
  const int slab = rem / NSTRIP;
  const int strip = rem % NSTRIP;
  const int img  = g * 8 + xcd;          // 0..47
  const int b    = img / CHAN;

  const int base = (slab == 0) ? 0 : (slab == 1 ? 244 : 256);
  const int lo   = (slab == 0) ? 0 : (slab == 1 ? 246 : 490);
  const int hi   = (slab == 0) ? 245 : (slab == 1 ? 489 : 501);

  const int r0 = strip * RPS;
  const int r1 = min(r0 + RPS, HO);
  if (r0 >= HO) return;
  const int c0 = base + 4 * t;           // lane's first col (16B aligned)

  const float* __restrict__ p1 = g1 + (size_t)img * HDIM * WDIM + c0;
  const float* __restrict__ p2 = g2 + (size_t)img * HDIM * WDIM + c0;

  // vertical sliding column sums, lane's 4 cols
  float s1[4], s2[4], sp[4], sq[4];
#pragma unroll
  for (int k = 0; k < 4; ++k) s1[k] = s2[k] = sp[k] = sq[k] = 0.f;

  float4 n1a, n1b, n1c, n2a, n2b, n2c;   // NEW 3-deep
  float4 o1, o2;                         // OLD

  auto ACC = [&](const float4& u, const float4& v) {
    float uu[4] = {u.x, u.y, u.z, u.w};
    float vv[4] = {v.x, v.y, v.z, v.w};
#pragma unroll
    for (int k = 0; k < 4; ++k) {
      float x = uu[k], y = vv[k];
      s1[k] += x;
      s2[k] += y;
      sp[k] = fmaf(x, y, sp[k]);
      sq[k] = fmaf(x, x, sq[k]);
      sq[k] = fmaf(y, y, sq[k]);
    }
  };
  auto DES = [&](const float4& u, const float4& v) {
    float uu[4] = {u.x, u.y, u.z, u.w};
    float vv[4] = {v.x, v.y, v.z, v.w};
#pragma unroll
    for (int k = 0; k < 4; ++k) {
      float x = uu[k], y = vv[k];
      s1[k] -= x;
      s2[k] -= y;
      sp[k] = fmaf(x, -y, sp[k]);
      sq[k] = fmaf(x, -x, sq[k]);
      sq[k] = fmaf(y, -y, sq[k]);
    }
  };

#define LDN(U, V, row)                                   \
  {                                                      \
    int rr_ = (row);                                     \
    U = *(const float4*)(p1 + (size_t)rr_ * WDIM);       \
    V = *(const float4*)(p2 + (size_t)rr_ * WDIM);       \
  }

  // ---- warm-up: accumulate rows r0..r0+9, 3-deep pipeline ----
  LDN(n1a, n2a, r0);
  LDN(n1b, n2b, r0 + 1);
  LDN(n1c, n2c, r0 + 2);
  ACC(n1a, n2a); LDN(n1a, n2a, r0 + 3);
  ACC(n1b, n2b); LDN(n1b, n2b, r0 + 4);
  ACC(n1c, n2c); LDN(n1c, n2c, r0 + 5);
  ACC(n1a, n2a); LDN(n1a, n2a, r0 + 6);
  ACC(n1b, n2b); LDN(n1b, n2b, r0 + 7);
  ACC(n1c, n2c); LDN(n1c, n2c, r0 + 8);
  ACC(n1a, n2a); LDN(n1a, n2a, r0 + 9);
  ACC(n1b, n2b); LDN(n1b, n2b, r0 + 10);
  ACC(n1c, n2c); LDN(n1c, n2c, r0 + 11);
  ACC(n1a, n2a); LDN(n1a, n2a, r0 + 12);
  // accumulated rows r0..r0+9; bufs: b=r+10, c=r+11, a=r+12 for r=r0

  float acc = 0.f;

  auto STEP = [&](int r, float4& N1, float4& N2) {
    ACC(N1, N2);                          // window = rows [r, r+10]
    LDN(N1, N2, min(r + 13, HDIM - 1));   // refill 3-deep NEW
    LDN(o1, o2, r);                       // OLD (13-row reuse: L1/L2 hit)

    // publish own 4 col-quads: sigma(4t+i) = i*64+t (conflict-free)
#pragma unroll
    for (int i = 0; i < 4; ++i)
      Q[i * 64 + t] = make_float4(s1[i], s2[i], sp[i], sq[i]);
    asm volatile("s_waitcnt lgkmcnt(0)" ::: "memory");

    // halo: col c0+4+m = quad (m&3)*64 + lane (t+1+(m>>2)), m=0..9
    float4 h[10];
#pragma unroll
    for (int m = 0; m < 10; ++m)
      h[m] = Q[(m & 3) * 64 + ((t + 1 + (m >> 2)) & 63)];

    // first window: cols c0..c0+10 = own 0..3 + halo 0..6
    float w1 = ((s1[0] + s1[1]) + (s1[2] + s1[3])) +
               ((h[0].x + h[1].x) + (h[2].x + h[3].x)) +
               ((h[4].x + h[5].x) + h[6].x);
    float w2 = ((s2[0] + s2[1]) + (s2[2] + s2[3])) +
               ((h[0].y + h[1].y) + (h[2].y + h[3].y)) +
               ((h[4].y + h[5].y) + h[6].y);
    float wp = ((sp[0] + sp[1]) + (sp[2] + sp[3])) +
               ((h[0].z + h[1].z) + (h[2].z + h[3].z)) +
               ((h[4].z + h[5].z) + h[6].z);
    float wq = ((sq[0] + sq[1]) + (sq[2] + sq[3])) +
               ((h[0].w + h[1].w) + (h[2].w + h[3].w)) +
               ((h[4].w + h[5].w) + h[6].w);

#pragma unroll
    for (int j = 0; j < 4; ++j) {
      if (j > 0) {  // slide: drop own col j-1, add halo col c0+j+10
        w1 = (w1 - s1[j - 1]) + h[6 + j].x;
        w2 = (w2 - s2[j - 1]) + h[6 + j].y;
        wp = (wp - sp[j - 1]) + h[6 + j].z;
        wq = (wq - sq[j - 1]) + h[6 + j].w;
      }
      // scale-folded SSIM (121^4 cancels in n/d)
      float s12 = w1 * w2;
      float msq = fmaf(w1, w1, w2 * w2);
      float N1_ = fmaf(2.f, s12, K1);
      float N2_ = fmaf(2.f, fmaf(W2F, wp, -s12), K2);
      float D1_ = msq + K1;
      float D2_ = fmaf(W2F, wq, -msq) + K2;
      float val = (N1_ * N2_) * __builtin_amdgcn_rcpf(D1_ * D2_);
      int c = c0 + j;
      acc += (c >= lo && c <= hi) ? val : 0.f;
    }

    DES(o1, o2);                          // slide out row r
  };

  // ---- main loop, 3x unrolled to keep buffer indices static ----
  for (int r = r0; r < r1; r += 3) {
    STEP(r, n1b, n2b);
    if (r + 1 < r1) STEP(r + 1, n1c, n2c);
    if (r + 2 < r1) STEP(r + 2, n1a, n2a);
  }
#undef LDN

  // wave reduction, banked double atomic
#pragma unroll
  for (int off = 32; off > 0; off >>= 1) acc += __shfl_down(acc, off, 64);
  if (t == 0) atomicAdd(&ws[b * NBANK + (blockIdx.x & (NBANK - 1))], (double)acc);
}

__global__ void ssim_finalize(const double* __restrict__ ws,
                              float* __restrict__ out) {
  int i = threadIdx.x;
  if (i < BATCH) {
    double s = 0.0;
#pragma unroll
    for (int k = 0; k < NBANK; ++k) s += ws[i * NBANK + k];
    out[i] = (float)(1.0 - s / ((double)CHAN * HO * WO));
  }
}

extern "C" void kernel_launch(void* const* d_in, const int* in_sizes, int n_in,
                              void* d_out, int out_size, void* d_ws,
                              size_t ws_size, hipStream_t stream) {
  const float* img1 = (const float*)d_in[0];
  const float* img2 = (const float*)d_in[1];
  float* out = (float*)d_out;
  double* ws = (double*)d_ws;

  hipMemsetAsync(d_ws, 0, BATCH * NBANK * sizeof(double), stream);
  ssim_main<<<dim3(NBLK), NTHR, 0, stream>>>(img1, img2, ws);
  ssim_finalize<<<1, 64, 0, stream>>>(ws, out);
}